// Round 2
// baseline (256.310 us; speedup 1.0000x reference)
//
#include <hip/hip_runtime.h>
#include <hip/hip_bf16.h>

#define BN   64
#define CIN  512
#define COUT 512
#define HW   784
#define NT   128
#define MT   112
#define BK   64

typedef __attribute__((ext_vector_type(8))) short short8;
typedef __attribute__((ext_vector_type(4))) float f32x4;

__device__ __forceinline__ unsigned short f2bf(float f) {
    union { float f; unsigned int u; } v; v.f = f;
    unsigned int r = v.u + 0x7fffu + ((v.u >> 16) & 1u);   // RNE
    return (unsigned short)(r >> 16);
}

__device__ __forceinline__ uint2 pack4(float a, float b, float c, float d) {
    uint2 r;
    r.x = (unsigned int)f2bf(a) | ((unsigned int)f2bf(b) << 16);
    r.y = (unsigned int)f2bf(c) | ((unsigned int)f2bf(d) << 16);
    return r;
}

// async global->LDS, 16B per lane; LDS dest = wave-uniform base + lane*16
__device__ __forceinline__ void gl_lds16(const unsigned short* g, unsigned short* l) {
    __builtin_amdgcn_global_load_lds(
        (const __attribute__((address_space(1))) unsigned int*)g,
        (__attribute__((address_space(3))) unsigned int*)l,
        16, 0, 0);
}

// ---------------- Pass 1: shift + fp32->bf16 + transpose to Xt[b][kk][hw][ck] ----------------
// grid (8, 7, 65); z==64 blocks convert W -> Wb (row-major [o][c] bf16).
__global__ __launch_bounds__(256)
void p1_shift_cvt(const float* __restrict__ x, const float* __restrict__ W,
                  unsigned short* __restrict__ Wb, unsigned short* __restrict__ Xt)
{
    const int t = threadIdx.x;
    if (blockIdx.z == BN) {
        // W convert: 56 blocks cover 32768 groups of 8 elements
        int wlin = blockIdx.x * 7 + blockIdx.y;           // 0..55
        for (int gi = wlin * 256 + t; gi < (COUT * CIN) / 8; gi += 56 * 256) {
            const float* p = W + (size_t)gi * 8;
            float4 a = *(const float4*)p;
            float4 c = *(const float4*)(p + 4);
            uint2 lo = pack4(a.x, a.y, a.z, a.w);
            uint2 hi = pack4(c.x, c.y, c.z, c.w);
            uint4 v; v.x = lo.x; v.y = lo.y; v.z = hi.x; v.w = hi.y;
            *(uint4*)(Wb + (size_t)gi * 8) = v;
        }
        return;
    }
    const int kk = blockIdx.x;            // 0..7  (c-block of 64)
    const int mt = blockIdx.y;            // 0..6  (hw-tile of 112)
    const int b  = blockIdx.z;            // 0..63
    const int g  = kk >> 1;               // shift group (wave-uniform)
    const int c0 = kk * BK;
    const int hw_base = mt * MT;
    const float* xb = x + (size_t)b * CIN * HW;
    unsigned short* Xb = Xt + (size_t)(b * 8 + kk) * HW * BK;

    #pragma unroll
    for (int e0 = 0; e0 < 2; ++e0) {
        int e = t + e0 * 256;
        if (e < (BK / 4) * (MT / 4)) {    // 448 items of 4c x 4hw
            int cq = e / 28;
            int mq = e - cq * 28;
            int hw = hw_base + mq * 4;
            const float* src = xb + (size_t)(c0 + cq * 4) * HW;
            float4 v0, v1, v2, v3;
            if (g < 2) {
                int shw = hw + (g == 0 ? 28 : HW - 28);
                if (shw >= HW) shw -= HW;
                v0 = *(const float4*)(src + 0 * HW + shw);
                v1 = *(const float4*)(src + 1 * HW + shw);
                v2 = *(const float4*)(src + 2 * HW + shw);
                v3 = *(const float4*)(src + 3 * HW + shw);
            } else {
                int h  = hw / 28;
                int w0 = hw - h * 28;
                int base = h * 28;
                #pragma unroll
                for (int j = 0; j < 4; ++j) {
                    const float* row = src + j * HW + base;
                    float4 a = *(const float4*)(row + w0);
                    float4 r;
                    if (g == 2) {
                        float ex = row[(w0 + 4 < 28) ? (w0 + 4) : 0];
                        r.x = a.y; r.y = a.z; r.z = a.w; r.w = ex;
                    } else {
                        float ex = row[(w0 == 0) ? 27 : (w0 - 1)];
                        r.x = ex; r.y = a.x; r.z = a.y; r.w = a.z;
                    }
                    if (j == 0) v0 = r; else if (j == 1) v1 = r;
                    else if (j == 2) v2 = r; else v3 = r;
                }
            }
            unsigned short* dst = Xb + (size_t)hw * BK + cq * 4;
            *(uint2*)(dst + 0 * BK) = pack4(v0.x, v1.x, v2.x, v3.x);
            *(uint2*)(dst + 1 * BK) = pack4(v0.y, v1.y, v2.y, v3.y);
            *(uint2*)(dst + 2 * BK) = pack4(v0.z, v1.z, v2.z, v3.z);
            *(uint2*)(dst + 3 * BK) = pack4(v0.w, v1.w, v2.w, v3.w);
        }
    }
}

// ---------------- Pass 2: bf16 GEMM via global_load_lds, xor chunk swizzle ----------------
__global__ __launch_bounds__(256)
void p2_gemm(const unsigned short* __restrict__ Wb, const unsigned short* __restrict__ Xt,
             const float* __restrict__ gamma, const float* __restrict__ beta,
             const float* __restrict__ rmean, const float* __restrict__ rvar,
             float* __restrict__ out)
{
    __shared__ unsigned short sW[NT * BK];   // 16 KB, chunk (o,cs) at slot cs^(o&7)
    __shared__ unsigned short sX[MT * BK];   // 14 KB, chunk (m,cs) at slot cs^(m&7)

    const int t  = threadIdx.x;
    const int ot = blockIdx.x;
    const int mt = blockIdx.y;
    const int b  = blockIdx.z;
    const int o_base  = ot * NT;
    const int hw_base = mt * MT;
    const int lane = t & 63;
    const int wv   = t >> 6;
    const int m16  = lane & 15;
    const int q    = lane >> 4;

    f32x4 acc[2][7];
    #pragma unroll
    for (int i = 0; i < 2; ++i)
        #pragma unroll
        for (int j = 0; j < 7; ++j)
            acc[i][j] = (f32x4){0.f, 0.f, 0.f, 0.f};

    #pragma unroll
    for (int kk = 0; kk < CIN / BK; ++kk) {
        const int k0 = kk * BK;
        // stage W tile: 128 rows x 128B = 16 wave-loads of 1KB
        const unsigned short* Wk = Wb + (size_t)o_base * CIN + k0;
        #pragma unroll
        for (int i = 0; i < 4; ++i) {
            int ci = wv * 4 + i;
            int ch = ci * 64 + lane;
            int ol = ch >> 3, sl = ch & 7;
            int cs = sl ^ (ol & 7);
            gl_lds16(Wk + (size_t)ol * CIN + cs * 8, &sW[ci * 512]);
        }
        // stage X tile: 112 rows x 128B = 14 wave-loads (contiguous 1KB runs in Xt)
        const unsigned short* Xk = Xt + ((size_t)(b * 8 + kk) * HW + hw_base) * BK;
        int nci = (wv < 2) ? 4 : 3;
        for (int i = 0; i < nci; ++i) {
            int ci = wv + 4 * i;
            int ch = ci * 64 + lane;
            int hl = ch >> 3, sl = ch & 7;
            int cs = sl ^ (hl & 7);
            gl_lds16(Xk + hl * BK + cs * 8, &sX[ci * 512]);
        }
        __syncthreads();

        #pragma unroll
        for (int ks = 0; ks < BK; ks += 32) {
            const int csb = (ks >> 3) + q;
            short8 af[2];
            #pragma unroll
            for (int bo = 0; bo < 2; ++bo) {
                int ro = wv * 32 + bo * 16 + m16;
                af[bo] = *(const short8*)(&sW[ro * BK + (csb ^ (ro & 7)) * 8]);
            }
            #pragma unroll
            for (int bm = 0; bm < 7; ++bm) {
                int m = bm * 16 + m16;
                short8 bf = *(const short8*)(&sX[m * BK + (csb ^ (m & 7)) * 8]);
                acc[0][bm] = __builtin_amdgcn_mfma_f32_16x16x32_bf16(af[0], bf, acc[0][bm], 0, 0, 0);
                acc[1][bm] = __builtin_amdgcn_mfma_f32_16x16x32_bf16(af[1], bf, acc[1][bm], 0, 0, 0);
            }
        }
        __syncthreads();
    }

    // epilogue: folded BN + ReLU
    float scl[2][4], shf[2][4];
    #pragma unroll
    for (int bo = 0; bo < 2; ++bo)
        #pragma unroll
        for (int r = 0; r < 4; ++r) {
            int o = o_base + wv * 32 + bo * 16 + q * 4 + r;
            float sc = gamma[o] * rsqrtf(rvar[o] + 1e-5f);
            scl[bo][r] = sc;
            shf[bo][r] = beta[o] - rmean[o] * sc;
        }
    float* outb = out + (size_t)b * COUT * HW;
    #pragma unroll
    for (int bo = 0; bo < 2; ++bo) {
        #pragma unroll
        for (int r = 0; r < 4; ++r) {
            int o = o_base + wv * 32 + bo * 16 + q * 4 + r;
            float* orow = outb + (size_t)o * HW + hw_base + m16;
            #pragma unroll
            for (int bm = 0; bm < 7; ++bm) {
                float y = acc[bo][bm][r] * scl[bo][r] + shf[bo][r];
                y = fmaxf(y, 0.f);
                __builtin_nontemporal_store(y, orow + bm * 16);
            }
        }
    }
}

// ---------------- Fallback: round-1 single-pass (fp32 W staged in-block) ----------------
#define SW_STRIDE 72
#define SX_STRIDE 64
__global__ __launch_bounds__(256, 2)
void shiftconv_fallback(const float* __restrict__ x, const float* __restrict__ Wf,
                        const float* __restrict__ gamma, const float* __restrict__ beta,
                        const float* __restrict__ rmean, const float* __restrict__ rvar,
                        float* __restrict__ out)
{
    __shared__ unsigned short sW[NT * SW_STRIDE];
    __shared__ unsigned short sX[MT * SX_STRIDE];
    const int t = threadIdx.x;
    const int ot = blockIdx.x, mt = blockIdx.y, b = blockIdx.z;
    const int o_base = ot * NT, hw_base = mt * MT;
    const float* xb = x + (size_t)b * CIN * HW;
    const int lane = t & 63, wv = t >> 6, m16 = lane & 15, q = lane >> 4;
    f32x4 acc[2][7];
    #pragma unroll
    for (int i = 0; i < 2; ++i)
        #pragma unroll
        for (int j = 0; j < 7; ++j) acc[i][j] = (f32x4){0.f, 0.f, 0.f, 0.f};
    #pragma unroll
    for (int kk = 0; kk < CIN / BK; ++kk) {
        const int k0 = kk * BK;
        const int g = k0 >> 7;
        #pragma unroll
        for (int e0 = 0; e0 < 2; ++e0) {
            int e = t + e0 * 256;
            if (e < (BK / 4) * (MT / 4)) {
                int cq = e / 28, mq = e - cq * 28;
                int hw = hw_base + mq * 4;
                const float* src = xb + (size_t)(k0 + cq * 4) * HW;
                float4 v0, v1, v2, v3;
                if (g < 2) {
                    int shw = hw + (g == 0 ? 28 : HW - 28);
                    if (shw >= HW) shw -= HW;
                    v0 = *(const float4*)(src + 0 * HW + shw);
                    v1 = *(const float4*)(src + 1 * HW + shw);
                    v2 = *(const float4*)(src + 2 * HW + shw);
                    v3 = *(const float4*)(src + 3 * HW + shw);
                } else {
                    int h = hw / 28, w0 = hw - h * 28, base = h * 28;
                    #pragma unroll
                    for (int j = 0; j < 4; ++j) {
                        const float* row = src + j * HW + base;
                        float4 a = *(const float4*)(row + w0);
                        float4 r;
                        if (g == 2) {
                            float ex = row[(w0 + 4 < 28) ? (w0 + 4) : 0];
                            r.x = a.y; r.y = a.z; r.z = a.w; r.w = ex;
                        } else {
                            float ex = row[(w0 == 0) ? 27 : (w0 - 1)];
                            r.x = ex; r.y = a.x; r.z = a.y; r.w = a.z;
                        }
                        if (j == 0) v0 = r; else if (j == 1) v1 = r;
                        else if (j == 2) v2 = r; else v3 = r;
                    }
                }
                int m0 = mq * 4;
                { int p = (cq + 5 * (m0 + 0)) & 15;
                  *(uint2*)(&sX[(m0 + 0) * SX_STRIDE + p * 4]) = pack4(v0.x, v1.x, v2.x, v3.x); }
                { int p = (cq + 5 * (m0 + 1)) & 15;
                  *(uint2*)(&sX[(m0 + 1) * SX_STRIDE + p * 4]) = pack4(v0.y, v1.y, v2.y, v3.y); }
                { int p = (cq + 5 * (m0 + 2)) & 15;
                  *(uint2*)(&sX[(m0 + 2) * SX_STRIDE + p * 4]) = pack4(v0.z, v1.z, v2.z, v3.z); }
                { int p = (cq + 5 * (m0 + 3)) & 15;
                  *(uint2*)(&sX[(m0 + 3) * SX_STRIDE + p * 4]) = pack4(v0.w, v1.w, v2.w, v3.w); }
            }
        }
        #pragma unroll
        for (int i = 0; i < 4; ++i) {
            int e = t + i * 256;
            int ol = e >> 3, kg = (e & 7) * 8;
            const float* wr = Wf + (size_t)(o_base + ol) * CIN + k0 + kg;
            float4 a = *(const float4*)(wr);
            float4 c = *(const float4*)(wr + 4);
            uint2 lo = pack4(a.x, a.y, a.z, a.w);
            uint2 hi = pack4(c.x, c.y, c.z, c.w);
            uint4 v; v.x = lo.x; v.y = lo.y; v.z = hi.x; v.w = hi.y;
            *(uint4*)(&sW[ol * SW_STRIDE + kg]) = v;
        }
        __syncthreads();
        #pragma unroll
        for (int ks = 0; ks < BK; ks += 32) {
            short8 afrag[2];
            #pragma unroll
            for (int bo = 0; bo < 2; ++bo) {
                int row = wv * 32 + bo * 16 + m16;
                afrag[bo] = *(const short8*)(&sW[row * SW_STRIDE + ks + q * 8]);
            }
            #pragma unroll
            for (int bm = 0; bm < 7; ++bm) {
                int m = bm * 16 + m16;
                int g0 = (ks >> 2) + 2 * q;
                int p0 = (g0 + 5 * m) & 15;
                int p1 = (g0 + 1 + 5 * m) & 15;
                uint2 lo = *(const uint2*)(&sX[m * SX_STRIDE + p0 * 4]);
                uint2 hi = *(const uint2*)(&sX[m * SX_STRIDE + p1 * 4]);
                union { uint2 u2[2]; short8 s; } fb;
                fb.u2[0] = lo; fb.u2[1] = hi;
                acc[0][bm] = __builtin_amdgcn_mfma_f32_16x16x32_bf16(afrag[0], fb.s, acc[0][bm], 0, 0, 0);
                acc[1][bm] = __builtin_amdgcn_mfma_f32_16x16x32_bf16(afrag[1], fb.s, acc[1][bm], 0, 0, 0);
            }
        }
        __syncthreads();
    }
    float scl[2][4], shf[2][4];
    #pragma unroll
    for (int bo = 0; bo < 2; ++bo)
        #pragma unroll
        for (int r = 0; r < 4; ++r) {
            int o = o_base + wv * 32 + bo * 16 + q * 4 + r;
            float sc = gamma[o] * rsqrtf(rvar[o] + 1e-5f);
            scl[bo][r] = sc;
            shf[bo][r] = beta[o] - rmean[o] * sc;
        }
    float* outb = out + (size_t)b * COUT * HW;
    #pragma unroll
    for (int bo = 0; bo < 2; ++bo)
        #pragma unroll
        for (int r = 0; r < 4; ++r) {
            int o = o_base + wv * 32 + bo * 16 + q * 4 + r;
            float* orow = outb + (size_t)o * HW + hw_base + m16;
            #pragma unroll
            for (int bm = 0; bm < 7; ++bm) {
                float y = acc[bo][bm][r] * scl[bo][r] + shf[bo][r];
                y = fmaxf(y, 0.f);
                __builtin_nontemporal_store(y, orow + bm * 16);
            }
        }
}

extern "C" void kernel_launch(void* const* d_in, const int* in_sizes, int n_in,
                              void* d_out, int out_size, void* d_ws, size_t ws_size,
                              hipStream_t stream)
{
    const float* x     = (const float*)d_in[0];
    const float* W     = (const float*)d_in[1];
    const float* gamma = (const float*)d_in[2];
    const float* beta  = (const float*)d_in[3];
    const float* rmean = (const float*)d_in[4];
    const float* rvar  = (const float*)d_in[5];
    float* out = (float*)d_out;

    const size_t wb_bytes = (size_t)COUT * CIN * 2;                 // 512 KB
    const size_t xt_bytes = (size_t)BN * CIN * HW * 2;              // ~51.4 MB
    if (ws_size >= wb_bytes + xt_bytes) {
        unsigned short* Wb = (unsigned short*)d_ws;
        unsigned short* Xt = (unsigned short*)((char*)d_ws + wb_bytes);
        dim3 g1(8, 7, BN + 1);
        p1_shift_cvt<<<g1, 256, 0, stream>>>(x, W, Wb, Xt);
        dim3 g2(COUT / NT, HW / MT, BN);
        p2_gemm<<<g2, 256, 0, stream>>>(Wb, Xt, gamma, beta, rmean, rvar, out);
    } else {
        dim3 grid(COUT / NT, HW / MT, BN);
        shiftconv_fallback<<<grid, 256, 0, stream>>>(x, W, gamma, beta, rmean, rvar, out);
    }
}

// Round 3
// 237.199 us; speedup vs baseline: 1.0806x; 1.0806x over previous
//
#include <hip/hip_runtime.h>
#include <hip/hip_bf16.h>

#define BN   64
#define CIN  512
#define COUT 512
#define HW   784
#define NT   128
#define MT   112
#define BK   64
#define TROW 68   /* p1 LDS row stride in ushorts (136 B: odd granule count) */

typedef __attribute__((ext_vector_type(8))) short short8;
typedef __attribute__((ext_vector_type(4))) float f32x4;

__device__ __forceinline__ unsigned short f2bf(float f) {
    union { float f; unsigned int u; } v; v.f = f;
    unsigned int r = v.u + 0x7fffu + ((v.u >> 16) & 1u);   // RNE
    return (unsigned short)(r >> 16);
}

__device__ __forceinline__ uint2 pack4(float a, float b, float c, float d) {
    uint2 r;
    r.x = (unsigned int)f2bf(a) | ((unsigned int)f2bf(b) << 16);
    r.y = (unsigned int)f2bf(c) | ((unsigned int)f2bf(d) << 16);
    return r;
}

__device__ __forceinline__ void gl_lds16(const unsigned short* g, unsigned short* l) {
    __builtin_amdgcn_global_load_lds(
        (const __attribute__((address_space(1))) unsigned int*)g,
        (__attribute__((address_space(3))) unsigned int*)l,
        16, 0, 0);
}

// ---------------- Pass 1: shift + cvt + LDS transpose -> coalesced Xt stores ----------------
// grid (8, 7, 65); z==64 blocks convert W -> bf16.
__global__ __launch_bounds__(256)
void p1_shift_cvt(const float* __restrict__ x, const float* __restrict__ W,
                  unsigned short* __restrict__ Wb, unsigned short* __restrict__ Xt)
{
    __shared__ unsigned short sT[MT * TROW];   // 15232 B
    const int t = threadIdx.x;
    if (blockIdx.z == BN) {
        int wlin = blockIdx.x * 7 + blockIdx.y;           // 0..55
        for (int gi = wlin * 256 + t; gi < (COUT * CIN) / 8; gi += 56 * 256) {
            const float* p = W + (size_t)gi * 8;
            float4 a = *(const float4*)p;
            float4 c = *(const float4*)(p + 4);
            uint2 lo = pack4(a.x, a.y, a.z, a.w);
            uint2 hi = pack4(c.x, c.y, c.z, c.w);
            uint4 v; v.x = lo.x; v.y = lo.y; v.z = hi.x; v.w = hi.y;
            *(uint4*)(Wb + (size_t)gi * 8) = v;
        }
        return;
    }
    const int kk = blockIdx.x;            // c-block of 64
    const int mt = blockIdx.y;            // hw-tile of 112
    const int b  = blockIdx.z;
    const int g  = kk >> 1;               // shift group (block-uniform)
    const int c0 = kk * BK;
    const int hw_base = mt * MT;
    const float* xb = x + (size_t)b * CIN * HW;

    // Phase A: gather-shift 4c x 4hw micro-tiles, transpose in regs, pack bf16 -> LDS
    #pragma unroll
    for (int e0 = 0; e0 < 2; ++e0) {
        int e = t + e0 * 256;
        if (e < (BK / 4) * (MT / 4)) {    // 448 items
            int cq = e / 28;
            int mq = e - cq * 28;
            int hw = hw_base + mq * 4;
            const float* src = xb + (size_t)(c0 + cq * 4) * HW;
            float4 v0, v1, v2, v3;
            if (g < 2) {
                int shw = hw + (g == 0 ? 28 : HW - 28);
                if (shw >= HW) shw -= HW;
                v0 = *(const float4*)(src + 0 * HW + shw);
                v1 = *(const float4*)(src + 1 * HW + shw);
                v2 = *(const float4*)(src + 2 * HW + shw);
                v3 = *(const float4*)(src + 3 * HW + shw);
            } else {
                int h  = hw / 28;
                int w0 = hw - h * 28;
                int base = h * 28;
                #pragma unroll
                for (int j = 0; j < 4; ++j) {
                    const float* row = src + j * HW + base;
                    float4 a = *(const float4*)(row + w0);
                    float4 r;
                    if (g == 2) {
                        float ex = row[(w0 + 4 < 28) ? (w0 + 4) : 0];
                        r.x = a.y; r.y = a.z; r.z = a.w; r.w = ex;
                    } else {
                        float ex = row[(w0 == 0) ? 27 : (w0 - 1)];
                        r.x = ex; r.y = a.x; r.z = a.y; r.w = a.z;
                    }
                    if (j == 0) v0 = r; else if (j == 1) v1 = r;
                    else if (j == 2) v2 = r; else v3 = r;
                }
            }
            int m0 = mq * 4;
            *(uint2*)(&sT[(m0 + 0) * TROW + cq * 4]) = pack4(v0.x, v1.x, v2.x, v3.x);
            *(uint2*)(&sT[(m0 + 1) * TROW + cq * 4]) = pack4(v0.y, v1.y, v2.y, v3.y);
            *(uint2*)(&sT[(m0 + 2) * TROW + cq * 4]) = pack4(v0.z, v1.z, v2.z, v3.z);
            *(uint2*)(&sT[(m0 + 3) * TROW + cq * 4]) = pack4(v0.w, v1.w, v2.w, v3.w);
        }
    }
    __syncthreads();

    // Phase B: coalesced 16B stores of [hw][64c] rows
    unsigned short* Xb = Xt + ((size_t)(b * 8 + kk) * HW + hw_base) * BK;
    for (int ch = t; ch < MT * 8; ch += 256) {   // 896 16B chunks
        int m = ch >> 3, j = ch & 7;
        uint2 a = *(const uint2*)(&sT[m * TROW + j * 8]);
        uint2 c = *(const uint2*)(&sT[m * TROW + j * 8 + 4]);
        uint4 v; v.x = a.x; v.y = a.y; v.z = c.x; v.w = c.y;
        *(uint4*)(Xb + (size_t)m * BK + j * 8) = v;   // regular store: keep Xt L2/L3-hot
    }
}

// ---------------- Pass 2: GEMM, W in registers, X dbuf via global_load_lds ----------------
__global__ __launch_bounds__(256, 2)
void p2_gemm(const unsigned short* __restrict__ Wb, const unsigned short* __restrict__ Xt,
             const float* __restrict__ gamma, const float* __restrict__ beta,
             const float* __restrict__ rmean, const float* __restrict__ rvar,
             float* __restrict__ out)
{
    __shared__ unsigned short sX[2][MT * BK];   // 2 x 14336 B

    const int t  = threadIdx.x;
    // XCD-pairing swizzle: 4 o-tile sharers of one X-slab at ids {base,+8,+16,+24}
    const int id   = blockIdx.x;                 // 0..1791
    const int ot   = (id >> 3) & 3;
    const int pair = ((id >> 5) << 3) | (id & 7);   // 0..447
    const int mt   = pair % 7;
    const int b    = pair / 7;
    const int o_base  = ot * NT;
    const int hw_base = mt * MT;
    const int lane = t & 63;
    const int wv   = t >> 6;
    const int m16  = lane & 15;
    const int q    = lane >> 4;

    const unsigned short* Xbase = Xt + ((size_t)(b * 8) * HW + hw_base) * BK;

    // stage X tile kk into buf: 14 wave-chunks of 64 lanes x 16B, xor-swizzled source
    auto stage = [&](int kk, unsigned short* buf) {
        const unsigned short* Xk = Xbase + (size_t)kk * HW * BK;
        int nci = (wv < 2) ? 4 : 3;
        for (int i = 0; i < nci; ++i) {
            int ci = wv + 4 * i;
            int ch = ci * 64 + lane;
            int hl = ch >> 3, sl = ch & 7;
            int cs = sl ^ (hl & 7);
            gl_lds16(Xk + hl * BK + cs * 8, &buf[ci * 512]);
        }
    };

    stage(0, sX[0]);

    // W preload: 16 k-steps x 2 o-frags = 128 VGPRs
    short8 wf[16][2];
    #pragma unroll
    for (int ki = 0; ki < 16; ++ki)
        #pragma unroll
        for (int bo = 0; bo < 2; ++bo) {
            int row = o_base + wv * 32 + bo * 16 + m16;
            wf[ki][bo] = *(const short8*)(Wb + (size_t)row * CIN + ki * 32 + q * 8);
        }

    f32x4 acc[2][7];
    #pragma unroll
    for (int i = 0; i < 2; ++i)
        #pragma unroll
        for (int j = 0; j < 7; ++j)
            acc[i][j] = (f32x4){0.f, 0.f, 0.f, 0.f};

    __syncthreads();   // sX[0] ready

    #pragma unroll
    for (int kk = 0; kk < CIN / BK; ++kk) {
        if (kk < 7) stage(kk + 1, sX[(kk + 1) & 1]);   // in flight during compute
        const unsigned short* xs = sX[kk & 1];
        #pragma unroll
        for (int ks = 0; ks < 2; ++ks) {
            short8 bf[7];
            #pragma unroll
            for (int bm = 0; bm < 7; ++bm) {
                int m  = bm * 16 + m16;
                int lc = ks * 4 + q;               // logical 16B chunk 0..7
                int sl = lc ^ (m & 7);
                bf[bm] = *(const short8*)(&xs[m * BK + sl * 8]);
            }
            #pragma unroll
            for (int bm = 0; bm < 7; ++bm) {
                acc[0][bm] = __builtin_amdgcn_mfma_f32_16x16x32_bf16(wf[kk * 2 + ks][0], bf[bm], acc[0][bm], 0, 0, 0);
                acc[1][bm] = __builtin_amdgcn_mfma_f32_16x16x32_bf16(wf[kk * 2 + ks][1], bf[bm], acc[1][bm], 0, 0, 0);
            }
        }
        __syncthreads();   // drains glds(kk+1) AFTER compute(kk); recycles buffers
    }

    float scl[2][4], shf[2][4];
    #pragma unroll
    for (int bo = 0; bo < 2; ++bo)
        #pragma unroll
        for (int r = 0; r < 4; ++r) {
            int o = o_base + wv * 32 + bo * 16 + q * 4 + r;
            float sc = gamma[o] * rsqrtf(rvar[o] + 1e-5f);
            scl[bo][r] = sc;
            shf[bo][r] = beta[o] - rmean[o] * sc;
        }
    float* outb = out + (size_t)b * COUT * HW;
    #pragma unroll
    for (int bo = 0; bo < 2; ++bo) {
        #pragma unroll
        for (int r = 0; r < 4; ++r) {
            int o = o_base + wv * 32 + bo * 16 + q * 4 + r;
            float* orow = outb + (size_t)o * HW + hw_base + m16;
            #pragma unroll
            for (int bm = 0; bm < 7; ++bm) {
                float y = acc[bo][bm][r] * scl[bo][r] + shf[bo][r];
                y = fmaxf(y, 0.f);
                __builtin_nontemporal_store(y, orow + bm * 16);
            }
        }
    }
}

// ---------------- Fallback (ws too small): round-1 single-pass ----------------
#define SW_STRIDE 72
#define SX_STRIDE 64
__global__ __launch_bounds__(256, 2)
void shiftconv_fallback(const float* __restrict__ x, const float* __restrict__ Wf,
                        const float* __restrict__ gamma, const float* __restrict__ beta,
                        const float* __restrict__ rmean, const float* __restrict__ rvar,
                        float* __restrict__ out)
{
    __shared__ unsigned short sW[NT * SW_STRIDE];
    __shared__ unsigned short sX[MT * SX_STRIDE];
    const int t = threadIdx.x;
    const int ot = blockIdx.x, mt = blockIdx.y, b = blockIdx.z;
    const int o_base = ot * NT, hw_base = mt * MT;
    const float* xb = x + (size_t)b * CIN * HW;
    const int lane = t & 63, wv = t >> 6, m16 = lane & 15, q = lane >> 4;
    f32x4 acc[2][7];
    #pragma unroll
    for (int i = 0; i < 2; ++i)
        #pragma unroll
        for (int j = 0; j < 7; ++j) acc[i][j] = (f32x4){0.f, 0.f, 0.f, 0.f};
    #pragma unroll
    for (int kk = 0; kk < CIN / BK; ++kk) {
        const int k0 = kk * BK;
        const int g = k0 >> 7;
        #pragma unroll
        for (int e0 = 0; e0 < 2; ++e0) {
            int e = t + e0 * 256;
            if (e < (BK / 4) * (MT / 4)) {
                int cq = e / 28, mq = e - cq * 28;
                int hw = hw_base + mq * 4;
                const float* src = xb + (size_t)(k0 + cq * 4) * HW;
                float4 v0, v1, v2, v3;
                if (g < 2) {
                    int shw = hw + (g == 0 ? 28 : HW - 28);
                    if (shw >= HW) shw -= HW;
                    v0 = *(const float4*)(src + 0 * HW + shw);
                    v1 = *(const float4*)(src + 1 * HW + shw);
                    v2 = *(const float4*)(src + 2 * HW + shw);
                    v3 = *(const float4*)(src + 3 * HW + shw);
                } else {
                    int h = hw / 28, w0 = hw - h * 28, base = h * 28;
                    #pragma unroll
                    for (int j = 0; j < 4; ++j) {
                        const float* row = src + j * HW + base;
                        float4 a = *(const float4*)(row + w0);
                        float4 r;
                        if (g == 2) {
                            float ex = row[(w0 + 4 < 28) ? (w0 + 4) : 0];
                            r.x = a.y; r.y = a.z; r.z = a.w; r.w = ex;
                        } else {
                            float ex = row[(w0 == 0) ? 27 : (w0 - 1)];
                            r.x = ex; r.y = a.x; r.z = a.y; r.w = a.z;
                        }
                        if (j == 0) v0 = r; else if (j == 1) v1 = r;
                        else if (j == 2) v2 = r; else v3 = r;
                    }
                }
                int m0 = mq * 4;
                { int p = (cq + 5 * (m0 + 0)) & 15;
                  *(uint2*)(&sX[(m0 + 0) * SX_STRIDE + p * 4]) = pack4(v0.x, v1.x, v2.x, v3.x); }
                { int p = (cq + 5 * (m0 + 1)) & 15;
                  *(uint2*)(&sX[(m0 + 1) * SX_STRIDE + p * 4]) = pack4(v0.y, v1.y, v2.y, v3.y); }
                { int p = (cq + 5 * (m0 + 2)) & 15;
                  *(uint2*)(&sX[(m0 + 2) * SX_STRIDE + p * 4]) = pack4(v0.z, v1.z, v2.z, v3.z); }
                { int p = (cq + 5 * (m0 + 3)) & 15;
                  *(uint2*)(&sX[(m0 + 3) * SX_STRIDE + p * 4]) = pack4(v0.w, v1.w, v2.w, v3.w); }
            }
        }
        #pragma unroll
        for (int i = 0; i < 4; ++i) {
            int e = t + i * 256;
            int ol = e >> 3, kg = (e & 7) * 8;
            const float* wr = Wf + (size_t)(o_base + ol) * CIN + k0 + kg;
            float4 a = *(const float4*)(wr);
            float4 c = *(const float4*)(wr + 4);
            uint2 lo = pack4(a.x, a.y, a.z, a.w);
            uint2 hi = pack4(c.x, c.y, c.z, c.w);
            uint4 v; v.x = lo.x; v.y = lo.y; v.z = hi.x; v.w = hi.y;
            *(uint4*)(&sW[ol * SW_STRIDE + kg]) = v;
        }
        __syncthreads();
        #pragma unroll
        for (int ks = 0; ks < BK; ks += 32) {
            short8 afrag[2];
            #pragma unroll
            for (int bo = 0; bo < 2; ++bo) {
                int row = wv * 32 + bo * 16 + m16;
                afrag[bo] = *(const short8*)(&sW[row * SW_STRIDE + ks + q * 8]);
            }
            #pragma unroll
            for (int bm = 0; bm < 7; ++bm) {
                int m = bm * 16 + m16;
                int g0 = (ks >> 2) + 2 * q;
                int p0 = (g0 + 5 * m) & 15;
                int p1 = (g0 + 1 + 5 * m) & 15;
                uint2 lo = *(const uint2*)(&sX[m * SX_STRIDE + p0 * 4]);
                uint2 hi = *(const uint2*)(&sX[m * SX_STRIDE + p1 * 4]);
                union { uint2 u2[2]; short8 s; } fb;
                fb.u2[0] = lo; fb.u2[1] = hi;
                acc[0][bm] = __builtin_amdgcn_mfma_f32_16x16x32_bf16(afrag[0], fb.s, acc[0][bm], 0, 0, 0);
                acc[1][bm] = __builtin_amdgcn_mfma_f32_16x16x32_bf16(afrag[1], fb.s, acc[1][bm], 0, 0, 0);
            }
        }
        __syncthreads();
    }
    float scl[2][4], shf[2][4];
    #pragma unroll
    for (int bo = 0; bo < 2; ++bo)
        #pragma unroll
        for (int r = 0; r < 4; ++r) {
            int o = o_base + wv * 32 + bo * 16 + q * 4 + r;
            float sc = gamma[o] * rsqrtf(rvar[o] + 1e-5f);
            scl[bo][r] = sc;
            shf[bo][r] = beta[o] - rmean[o] * sc;
        }
    float* outb = out + (size_t)b * COUT * HW;
    #pragma unroll
    for (int bo = 0; bo < 2; ++bo)
        #pragma unroll
        for (int r = 0; r < 4; ++r) {
            int o = o_base + wv * 32 + bo * 16 + q * 4 + r;
            float* orow = outb + (size_t)o * HW + hw_base + m16;
            #pragma unroll
            for (int bm = 0; bm < 7; ++bm) {
                float y = acc[bo][bm][r] * scl[bo][r] + shf[bo][r];
                y = fmaxf(y, 0.f);
                __builtin_nontemporal_store(y, orow + bm * 16);
            }
        }
}

extern "C" void kernel_launch(void* const* d_in, const int* in_sizes, int n_in,
                              void* d_out, int out_size, void* d_ws, size_t ws_size,
                              hipStream_t stream)
{
    const float* x     = (const float*)d_in[0];
    const float* W     = (const float*)d_in[1];
    const float* gamma = (const float*)d_in[2];
    const float* beta  = (const float*)d_in[3];
    const float* rmean = (const float*)d_in[4];
    const float* rvar  = (const float*)d_in[5];
    float* out = (float*)d_out;

    const size_t wb_bytes = (size_t)COUT * CIN * 2;                 // 512 KB
    const size_t xt_bytes = (size_t)BN * CIN * HW * 2;              // ~51.4 MB
    if (ws_size >= wb_bytes + xt_bytes) {
        unsigned short* Wb = (unsigned short*)d_ws;
        unsigned short* Xt = (unsigned short*)((char*)d_ws + wb_bytes);
        dim3 g1(8, 7, BN + 1);
        p1_shift_cvt<<<g1, 256, 0, stream>>>(x, W, Wb, Xt);
        p2_gemm<<<1792, 256, 0, stream>>>(Wb, Xt, gamma, beta, rmean, rvar, out);
    } else {
        dim3 grid(COUT / NT, HW / MT, BN);
        shiftconv_fallback<<<grid, 256, 0, stream>>>(x, W, gamma, beta, rmean, rvar, out);
    }
}

// Round 4
// 227.672 us; speedup vs baseline: 1.1258x; 1.0418x over previous
//
#include <hip/hip_runtime.h>
#include <hip/hip_bf16.h>

#define BN   64
#define CIN  512
#define COUT 512
#define HW   784
#define NT   128
#define MT   112
#define BK   64
#define TROW 68   /* 17 granules x 8B = 136 B rows */

typedef __attribute__((ext_vector_type(8))) short short8;
typedef __attribute__((ext_vector_type(4))) float f32x4;

__device__ __forceinline__ unsigned short f2bf(float f) {
    union { float f; unsigned int u; } v; v.f = f;
    unsigned int r = v.u + 0x7fffu + ((v.u >> 16) & 1u);   // RNE
    return (unsigned short)(r >> 16);
}

__device__ __forceinline__ uint2 pack4(float a, float b, float c, float d) {
    uint2 r;
    r.x = (unsigned int)f2bf(a) | ((unsigned int)f2bf(b) << 16);
    r.y = (unsigned int)f2bf(c) | ((unsigned int)f2bf(d) << 16);
    return r;
}

__device__ __forceinline__ void gl_lds16(const unsigned short* g, unsigned short* l) {
    __builtin_amdgcn_global_load_lds(
        (const __attribute__((address_space(1))) unsigned int*)g,
        (__attribute__((address_space(3))) unsigned int*)l,
        16, 0, 0);
}

// ---------------- Pass 1: shift + cvt + LDS transpose (mod-17 swizzle) ----------------
// grid (8, 7, 65), 448 threads; z==64 blocks convert W -> bf16.
__global__ __launch_bounds__(448)
void p1_shift_cvt(const float* __restrict__ x, const float* __restrict__ W,
                  unsigned short* __restrict__ Wb, unsigned short* __restrict__ Xt)
{
    __shared__ unsigned short sT[MT * TROW];   // 15232 B
    const int t = threadIdx.x;
    if (blockIdx.z == BN) {
        int wlin = blockIdx.x * 7 + blockIdx.y;           // 0..55
        for (int gi = wlin * 448 + t; gi < (COUT * CIN) / 8; gi += 56 * 448) {
            const float* p = W + (size_t)gi * 8;
            float4 a = *(const float4*)p;
            float4 c = *(const float4*)(p + 4);
            uint2 lo = pack4(a.x, a.y, a.z, a.w);
            uint2 hi = pack4(c.x, c.y, c.z, c.w);
            uint4 v; v.x = lo.x; v.y = lo.y; v.z = hi.x; v.w = hi.y;
            *(uint4*)(Wb + (size_t)gi * 8) = v;
        }
        return;
    }
    const int kk = blockIdx.x;            // c-block of 64
    const int mt = blockIdx.y;            // hw-tile of 112
    const int b  = blockIdx.z;
    const int g  = kk >> 1;               // shift group (block-uniform)
    const int c0 = kk * BK;
    const int hw_base = mt * MT;
    const float* xb = x + (size_t)b * CIN * HW;

    // Phase A: one 4c x 4hw micro-tile per lane (448 items, 448 lanes)
    {
        const int cq = t / 28;            // 0..15
        const int mq = t - cq * 28;       // 0..27
        const int hw = hw_base + mq * 4;
        const float* src = xb + (size_t)(c0 + cq * 4) * HW;
        float4 v0, v1, v2, v3;
        if (g < 2) {
            int shw = hw + (g == 0 ? 28 : HW - 28);
            if (shw >= HW) shw -= HW;
            v0 = *(const float4*)(src + 0 * HW + shw);
            v1 = *(const float4*)(src + 1 * HW + shw);
            v2 = *(const float4*)(src + 2 * HW + shw);
            v3 = *(const float4*)(src + 3 * HW + shw);
        } else {
            int h  = hw / 28;
            int w0 = hw - h * 28;
            int base = h * 28;
            #pragma unroll
            for (int j = 0; j < 4; ++j) {
                const float* row = src + j * HW + base;
                float4 a = *(const float4*)(row + w0);
                float4 r;
                if (g == 2) {
                    float ex = row[(w0 + 4 < 28) ? (w0 + 4) : 0];
                    r.x = a.y; r.y = a.z; r.z = a.w; r.w = ex;
                } else {
                    float ex = row[(w0 == 0) ? 27 : (w0 - 1)];
                    r.x = ex; r.y = a.x; r.z = a.y; r.w = a.z;
                }
                if (j == 0) v0 = r; else if (j == 1) v1 = r;
                else if (j == 2) v2 = r; else v3 = r;
            }
        }
        const int m0 = mq * 4;
        const int p  = (cq + mq) % 17;    // granule swizzle: bank step 10 mod 32
        *(uint2*)(&sT[(m0 + 0) * TROW + p * 4]) = pack4(v0.x, v1.x, v2.x, v3.x);
        *(uint2*)(&sT[(m0 + 1) * TROW + p * 4]) = pack4(v0.y, v1.y, v2.y, v3.y);
        *(uint2*)(&sT[(m0 + 2) * TROW + p * 4]) = pack4(v0.z, v1.z, v2.z, v3.z);
        *(uint2*)(&sT[(m0 + 3) * TROW + p * 4]) = pack4(v0.w, v1.w, v2.w, v3.w);
    }
    __syncthreads();

    // Phase B: coalesced 16B stores of [hw][64c] rows
    unsigned short* Xb = Xt + ((size_t)(b * 8 + kk) * HW + hw_base) * BK;
    #pragma unroll
    for (int e0 = 0; e0 < 2; ++e0) {
        int ch = t + e0 * 448;            // 896 chunks
        int m = ch >> 3, j = ch & 7;
        int q4 = m >> 2;
        int p0 = (2 * j + q4) % 17;
        int p1 = (2 * j + 1 + q4) % 17;
        uint2 a = *(const uint2*)(&sT[m * TROW + p0 * 4]);
        uint2 c = *(const uint2*)(&sT[m * TROW + p1 * 4]);
        uint4 v; v.x = a.x; v.y = a.y; v.z = c.x; v.w = c.y;
        *(uint4*)(Xb + (size_t)m * BK + j * 8) = v;   // regular store: keep Xt L2/L3-hot
    }
}

// ---------------- Pass 2: GEMM, W reg-streamed (2-deep), X dbuf via glds ----------------
__global__ __launch_bounds__(256, 2)
void p2_gemm(const unsigned short* __restrict__ Wb, const unsigned short* __restrict__ Xt,
             const float* __restrict__ gamma, const float* __restrict__ beta,
             const float* __restrict__ rmean, const float* __restrict__ rvar,
             float* __restrict__ out)
{
    __shared__ unsigned short sX[2][MT * BK];   // 2 x 14336 B

    const int t  = threadIdx.x;
    // XCD-pairing swizzle: 4 o-tile sharers of one X-slab at ids {base,+8,+16,+24}
    const int id   = blockIdx.x;                 // 0..1791
    const int ot   = (id >> 3) & 3;
    const int pair = ((id >> 5) << 3) | (id & 7);   // 0..447
    const int mt   = pair % 7;
    const int b    = pair / 7;
    const int o_base  = ot * NT;
    const int hw_base = mt * MT;
    const int lane = t & 63;
    const int wv   = t >> 6;
    const int m16  = lane & 15;
    const int q    = lane >> 4;

    const unsigned short* Xbase = Xt + ((size_t)(b * 8) * HW + hw_base) * BK;

    auto stage = [&](int kk, int bufi) {
        unsigned short* buf = sX[bufi];
        const unsigned short* Xk = Xbase + (size_t)kk * HW * BK;
        int nci = (wv < 2) ? 4 : 3;
        for (int i = 0; i < nci; ++i) {
            int ci = wv + 4 * i;
            int ch = ci * 64 + lane;
            int hl = ch >> 3, sl = ch & 7;
            int cs = sl ^ (hl & 7);
            gl_lds16(Xk + hl * BK + cs * 8, &buf[ci * 512]);
        }
    };

    // per-wave W row pointers (bo = 0,1), k offset in ushorts
    const unsigned short* wrow0 = Wb + (size_t)(o_base + wv * 32 + m16) * CIN + q * 8;
    const unsigned short* wrow1 = wrow0 + 16 * CIN;

    f32x4 acc[2][7];
    #pragma unroll
    for (int i = 0; i < 2; ++i)
        #pragma unroll
        for (int j = 0; j < 7; ++j)
            acc[i][j] = (f32x4){0.f, 0.f, 0.f, 0.f};

    short8 wc[2][2], wn[2][2];   // [ks][bo] current / next
    stage(0, 0);
    wc[0][0] = *(const short8*)(wrow0);
    wc[0][1] = *(const short8*)(wrow1);
    wc[1][0] = *(const short8*)(wrow0 + 32);
    wc[1][1] = *(const short8*)(wrow1 + 32);
    __syncthreads();   // sX[0] ready

#define COMPUTE(XS, WF)                                                          \
    {                                                                            \
        const unsigned short* xs = (XS);                                         \
        _Pragma("unroll")                                                        \
        for (int ks = 0; ks < 2; ++ks) {                                         \
            _Pragma("unroll")                                                    \
            for (int bm = 0; bm < 7; ++bm) {                                     \
                int m  = bm * 16 + m16;                                          \
                int lc = ks * 4 + q;                                             \
                int sl = lc ^ (m & 7);                                           \
                short8 bf = *(const short8*)(&xs[m * BK + sl * 8]);              \
                acc[0][bm] = __builtin_amdgcn_mfma_f32_16x16x32_bf16(WF[ks][0], bf, acc[0][bm], 0, 0, 0); \
                acc[1][bm] = __builtin_amdgcn_mfma_f32_16x16x32_bf16(WF[ks][1], bf, acc[1][bm], 0, 0, 0); \
            }                                                                    \
        }                                                                        \
    }

    #pragma unroll 1
    for (int kp = 0; kp < 4; ++kp) {
        {   // kk = 2*kp (even) -> compute buf0, prefetch buf1 + wn
            const int kn = 2 * kp + 1;
            stage(kn, 1);
            wn[0][0] = *(const short8*)(wrow0 + kn * 64);
            wn[0][1] = *(const short8*)(wrow1 + kn * 64);
            wn[1][0] = *(const short8*)(wrow0 + kn * 64 + 32);
            wn[1][1] = *(const short8*)(wrow1 + kn * 64 + 32);
            COMPUTE(sX[0], wc);
            __syncthreads();
        }
        {   // kk = 2*kp+1 (odd) -> compute buf1, prefetch buf0 + wc
            const int kn = 2 * kp + 2;
            if (kn < 8) {
                stage(kn, 0);
                wc[0][0] = *(const short8*)(wrow0 + kn * 64);
                wc[0][1] = *(const short8*)(wrow1 + kn * 64);
                wc[1][0] = *(const short8*)(wrow0 + kn * 64 + 32);
                wc[1][1] = *(const short8*)(wrow1 + kn * 64 + 32);
            }
            COMPUTE(sX[1], wn);
            __syncthreads();
        }
    }
#undef COMPUTE

    float scl[2][4], shf[2][4];
    #pragma unroll
    for (int bo = 0; bo < 2; ++bo)
        #pragma unroll
        for (int r = 0; r < 4; ++r) {
            int o = o_base + wv * 32 + bo * 16 + q * 4 + r;
            float sc = gamma[o] * rsqrtf(rvar[o] + 1e-5f);
            scl[bo][r] = sc;
            shf[bo][r] = beta[o] - rmean[o] * sc;
        }
    float* outb = out + (size_t)b * COUT * HW;
    #pragma unroll
    for (int bo = 0; bo < 2; ++bo) {
        #pragma unroll
        for (int r = 0; r < 4; ++r) {
            int o = o_base + wv * 32 + bo * 16 + q * 4 + r;
            float* orow = outb + (size_t)o * HW + hw_base + m16;
            #pragma unroll
            for (int bm = 0; bm < 7; ++bm) {
                float y = acc[bo][bm][r] * scl[bo][r] + shf[bo][r];
                y = fmaxf(y, 0.f);
                __builtin_nontemporal_store(y, orow + bm * 16);
            }
        }
    }
}

// ---------------- Fallback (ws too small): round-1 single-pass ----------------
#define SW_STRIDE 72
#define SX_STRIDE 64
__global__ __launch_bounds__(256, 2)
void shiftconv_fallback(const float* __restrict__ x, const float* __restrict__ Wf,
                        const float* __restrict__ gamma, const float* __restrict__ beta,
                        const float* __restrict__ rmean, const float* __restrict__ rvar,
                        float* __restrict__ out)
{
    __shared__ unsigned short sW[NT * SW_STRIDE];
    __shared__ unsigned short sX[MT * SX_STRIDE];
    const int t = threadIdx.x;
    const int ot = blockIdx.x, mt = blockIdx.y, b = blockIdx.z;
    const int o_base = ot * NT, hw_base = mt * MT;
    const float* xb = x + (size_t)b * CIN * HW;
    const int lane = t & 63, wv = t >> 6, m16 = lane & 15, q = lane >> 4;
    f32x4 acc[2][7];
    #pragma unroll
    for (int i = 0; i < 2; ++i)
        #pragma unroll
        for (int j = 0; j < 7; ++j) acc[i][j] = (f32x4){0.f, 0.f, 0.f, 0.f};
    #pragma unroll
    for (int kk = 0; kk < CIN / BK; ++kk) {
        const int k0 = kk * BK;
        const int g = k0 >> 7;
        #pragma unroll
        for (int e0 = 0; e0 < 2; ++e0) {
            int e = t + e0 * 256;
            if (e < (BK / 4) * (MT / 4)) {
                int cq = e / 28, mq = e - cq * 28;
                int hw = hw_base + mq * 4;
                const float* src = xb + (size_t)(k0 + cq * 4) * HW;
                float4 v0, v1, v2, v3;
                if (g < 2) {
                    int shw = hw + (g == 0 ? 28 : HW - 28);
                    if (shw >= HW) shw -= HW;
                    v0 = *(const float4*)(src + 0 * HW + shw);
                    v1 = *(const float4*)(src + 1 * HW + shw);
                    v2 = *(const float4*)(src + 2 * HW + shw);
                    v3 = *(const float4*)(src + 3 * HW + shw);
                } else {
                    int h = hw / 28, w0 = hw - h * 28, base = h * 28;
                    #pragma unroll
                    for (int j = 0; j < 4; ++j) {
                        const float* row = src + j * HW + base;
                        float4 a = *(const float4*)(row + w0);
                        float4 r;
                        if (g == 2) {
                            float ex = row[(w0 + 4 < 28) ? (w0 + 4) : 0];
                            r.x = a.y; r.y = a.z; r.z = a.w; r.w = ex;
                        } else {
                            float ex = row[(w0 == 0) ? 27 : (w0 - 1)];
                            r.x = ex; r.y = a.x; r.z = a.y; r.w = a.z;
                        }
                        if (j == 0) v0 = r; else if (j == 1) v1 = r;
                        else if (j == 2) v2 = r; else v3 = r;
                    }
                }
                int m0 = mq * 4;
                { int p = (cq + 5 * (m0 + 0)) & 15;
                  *(uint2*)(&sX[(m0 + 0) * SX_STRIDE + p * 4]) = pack4(v0.x, v1.x, v2.x, v3.x); }
                { int p = (cq + 5 * (m0 + 1)) & 15;
                  *(uint2*)(&sX[(m0 + 1) * SX_STRIDE + p * 4]) = pack4(v0.y, v1.y, v2.y, v3.y); }
                { int p = (cq + 5 * (m0 + 2)) & 15;
                  *(uint2*)(&sX[(m0 + 2) * SX_STRIDE + p * 4]) = pack4(v0.z, v1.z, v2.z, v3.z); }
                { int p = (cq + 5 * (m0 + 3)) & 15;
                  *(uint2*)(&sX[(m0 + 3) * SX_STRIDE + p * 4]) = pack4(v0.w, v1.w, v2.w, v3.w); }
            }
        }
        #pragma unroll
        for (int i = 0; i < 4; ++i) {
            int e = t + i * 256;
            int ol = e >> 3, kg = (e & 7) * 8;
            const float* wr = Wf + (size_t)(o_base + ol) * CIN + k0 + kg;
            float4 a = *(const float4*)(wr);
            float4 c = *(const float4*)(wr + 4);
            uint2 lo = pack4(a.x, a.y, a.z, a.w);
            uint2 hi = pack4(c.x, c.y, c.z, c.w);
            uint4 v; v.x = lo.x; v.y = lo.y; v.z = hi.x; v.w = hi.y;
            *(uint4*)(&sW[ol * SW_STRIDE + kg]) = v;
        }
        __syncthreads();
        #pragma unroll
        for (int ks = 0; ks < BK; ks += 32) {
            short8 afrag[2];
            #pragma unroll
            for (int bo = 0; bo < 2; ++bo) {
                int row = wv * 32 + bo * 16 + m16;
                afrag[bo] = *(const short8*)(&sW[row * SW_STRIDE + ks + q * 8]);
            }
            #pragma unroll
            for (int bm = 0; bm < 7; ++bm) {
                int m = bm * 16 + m16;
                int g0 = (ks >> 2) + 2 * q;
                int p0 = (g0 + 5 * m) & 15;
                int p1 = (g0 + 1 + 5 * m) & 15;
                uint2 lo = *(const uint2*)(&sX[m * SX_STRIDE + p0 * 4]);
                uint2 hi = *(const uint2*)(&sX[m * SX_STRIDE + p1 * 4]);
                union { uint2 u2[2]; short8 s; } fb;
                fb.u2[0] = lo; fb.u2[1] = hi;
                acc[0][bm] = __builtin_amdgcn_mfma_f32_16x16x32_bf16(afrag[0], fb.s, acc[0][bm], 0, 0, 0);
                acc[1][bm] = __builtin_amdgcn_mfma_f32_16x16x32_bf16(afrag[1], fb.s, acc[1][bm], 0, 0, 0);
            }
        }
        __syncthreads();
    }
    float scl[2][4], shf[2][4];
    #pragma unroll
    for (int bo = 0; bo < 2; ++bo)
        #pragma unroll
        for (int r = 0; r < 4; ++r) {
            int o = o_base + wv * 32 + bo * 16 + q * 4 + r;
            float sc = gamma[o] * rsqrtf(rvar[o] + 1e-5f);
            scl[bo][r] = sc;
            shf[bo][r] = beta[o] - rmean[o] * sc;
        }
    float* outb = out + (size_t)b * COUT * HW;
    #pragma unroll
    for (int bo = 0; bo < 2; ++bo)
        #pragma unroll
        for (int r = 0; r < 4; ++r) {
            int o = o_base + wv * 32 + bo * 16 + q * 4 + r;
            float* orow = outb + (size_t)o * HW + hw_base + m16;
            #pragma unroll
            for (int bm = 0; bm < 7; ++bm) {
                float y = acc[bo][bm][r] * scl[bo][r] + shf[bo][r];
                y = fmaxf(y, 0.f);
                __builtin_nontemporal_store(y, orow + bm * 16);
            }
        }
}

extern "C" void kernel_launch(void* const* d_in, const int* in_sizes, int n_in,
                              void* d_out, int out_size, void* d_ws, size_t ws_size,
                              hipStream_t stream)
{
    const float* x     = (const float*)d_in[0];
    const float* W     = (const float*)d_in[1];
    const float* gamma = (const float*)d_in[2];
    const float* beta  = (const float*)d_in[3];
    const float* rmean = (const float*)d_in[4];
    const float* rvar  = (const float*)d_in[5];
    float* out = (float*)d_out;

    const size_t wb_bytes = (size_t)COUT * CIN * 2;                 // 512 KB
    const size_t xt_bytes = (size_t)BN * CIN * HW * 2;              // ~51.4 MB
    if (ws_size >= wb_bytes + xt_bytes) {
        unsigned short* Wb = (unsigned short*)d_ws;
        unsigned short* Xt = (unsigned short*)((char*)d_ws + wb_bytes);
        dim3 g1(8, 7, BN + 1);
        p1_shift_cvt<<<g1, 448, 0, stream>>>(x, W, Wb, Xt);
        p2_gemm<<<1792, 256, 0, stream>>>(Wb, Xt, gamma, beta, rmean, rvar, out);
    } else {
        dim3 grid(COUT / NT, HW / MT, BN);
        shiftconv_fallback<<<grid, 256, 0, stream>>>(x, W, gamma, beta, rmean, rvar, out);
    }
}